// Round 5
// baseline (189.032 us; speedup 1.0000x reference)
//
#include <hip/hip_runtime.h>
#include <math.h>

#define BATCH 16384
#define LBL   512
#define HID   768
#define TR    128

typedef unsigned long long u64;
typedef unsigned short ushort_t;
typedef __attribute__((ext_vector_type(8))) short short8;
typedef __attribute__((ext_vector_type(4))) float f32x4;

__device__ __forceinline__ ushort_t f2bf(float f){
  unsigned u = __builtin_bit_cast(unsigned, f);
  u += 0x7FFFu + ((u >> 16) & 1u);
  return (ushort_t)(u >> 16);
}
__device__ __forceinline__ short8 pack8(float4 x, float4 y){
  short8 v;
  v[0]=(short)f2bf(x.x); v[1]=(short)f2bf(x.y); v[2]=(short)f2bf(x.z); v[3]=(short)f2bf(x.w);
  v[4]=(short)f2bf(y.x); v[5]=(short)f2bf(y.y); v[6]=(short)f2bf(y.z); v[7]=(short)f2bf(y.w);
  return v;
}
// HW packed f32->bf16 (RNE, identical result to f2bf): 4 inst instead of ~56.
__device__ __forceinline__ short8 pack8_cvt(float4 x, float4 y){
  union { short8 s; unsigned u[4]; } r;
  asm("v_cvt_pk_bf16_f32 %0, %1, %2" : "=v"(r.u[0]) : "v"(x.x), "v"(x.y));
  asm("v_cvt_pk_bf16_f32 %0, %1, %2" : "=v"(r.u[1]) : "v"(x.z), "v"(x.w));
  asm("v_cvt_pk_bf16_f32 %0, %1, %2" : "=v"(r.u[2]) : "v"(y.x), "v"(y.y));
  asm("v_cvt_pk_bf16_f32 %0, %1, %2" : "=v"(r.u[3]) : "v"(y.z), "v"(y.w));
  return r.s;
}
__device__ __forceinline__ float softplusf(float x){
  return fmaxf(x, 0.0f) + log1pf(expf(-fabsf(x)));
}
__device__ __forceinline__ void gload_lds16(const void* g, void* l){
  __builtin_amdgcn_global_load_lds((const __attribute__((address_space(1))) void*)g,
                                   (__attribute__((address_space(3))) void*)l, 16, 0, 0);
}

// ============ k1: M = W0a@Wt (swizzled bf16) | bias/KV | G = (labe@Wl^T)@W0b^T ============
// Swizzle: element (n, k) of a [128 n][768 k] B-matrix at ((k>>3)<<10) + (n<<3) + (k&7);
// chunk kc (64 k) = contiguous 16 KB at elem offset kc*8192 -> global_load_lds ready.
__global__ __launch_bounds__(256) void k1(
    const float* __restrict__ W0, const float* __restrict__ Wt, const float* __restrict__ Wl,
    const float* __restrict__ bt, const float* __restrict__ bl, const float* __restrict__ b0,
    const float* __restrict__ W1, const float* __restrict__ labe,
    ushort_t* __restrict__ Msw, ushort_t* __restrict__ W1B, ushort_t* __restrict__ Gt,
    float* __restrict__ KV, float* __restrict__ out){
  __shared__ __align__(16) char uni[50688];
  int bi = blockIdx.x, t = threadIdx.x;
  if (bi < 128){
    // ---- M row bi ----
    float* sw = (float*)uni;
    int i = bi;
    if (t < TR) sw[t] = W0[(size_t)i*256 + t];
    if (t < 128) W1B[i*128 + t] = f2bf(W1[i*128 + t]);
    __syncthreads();
    int c = t;
    float a0 = 0.f, a1 = 0.f, a2 = 0.f;
    #pragma unroll 8
    for (int a = 0; a < 128; a++){
      float w = sw[a];
      const float* r = Wt + (size_t)a*HID;
      a0 = fmaf(w, r[c], a0);
      a1 = fmaf(w, r[c+256], a1);
      a2 = fmaf(w, r[c+512], a2);
    }
    int c7 = c & 7;
    Msw[(((c      )>>3)<<10) + (i<<3) + c7] = f2bf(a0);
    Msw[(((c + 256)>>3)<<10) + (i<<3) + c7] = f2bf(a1);
    Msw[(((c + 512)>>3)<<10) + (i<<3) + c7] = f2bf(a2);
  } else if (bi == 128){
    // ---- KV = b0 + W0a@bt + W0b@bl, zero out ----
    if (t < TR){
      float s = b0[t];
      const float* r = W0 + (size_t)t*256;
      for (int a = 0; a < 128; a++) s = fmaf(r[a], bt[a], s);
      for (int a = 0; a < 128; a++) s = fmaf(r[128+a], bl[a], s);
      KV[t] = s;
    }
    if (t == 0) out[0] = 0.f;
  } else {
    // ---- G-block: 32 label rows l0..l0+31 ----
    int gi = bi - 129, l0 = gi * 32;
    int lane = t & 63, wave = t >> 6;          // 4 waves
    int m = lane & 15, q = lane >> 4;
    ushort_t* Bs1 = (ushort_t*)uni;
    ushort_t* As1 = (ushort_t*)(uni + 32768);
    ushort_t* Pl  = (ushort_t*)(uni + 41984);

    // stage-1: P[32][128] = labe[l0..] @ Wl^T, K=768
    int ar = t >> 3, ak = (t & 7) * 8;
    const float* apl = labe + (size_t)(l0 + ar)*HID + ak;
    int aB = t & 127, kh = t >> 7;
    const float* wlr = Wl + (size_t)aB*HID + kh*32;

    float4 ra0 = *(const float4*)apl;
    float4 ra1 = *(const float4*)(apl + 4);
    f32x4 accP[2][2];
    #pragma unroll
    for (int rt = 0; rt < 2; rt++)
      #pragma unroll
      for (int ct = 0; ct < 2; ct++) accP[rt][ct] = (f32x4){0.f,0.f,0.f,0.f};

    for (int c = 0; c < 12; c++){
      int buf = c & 1;
      #pragma unroll
      for (int j = 0; j < 4; j++){
        float4 w0v = *(const float4*)(wlr + c*64 + j*8);
        float4 w1v = *(const float4*)(wlr + c*64 + j*8 + 4);
        *(short8*)(Bs1 + buf*8192 + (kh*4 + j)*1024 + aB*8) = pack8(w0v, w1v);
      }
      *(short8*)(As1 + (size_t)(buf*32 + ar)*72 + ak) = pack8(ra0, ra1);
      __syncthreads();
      if (c < 11){
        ra0 = *(const float4*)(apl + (c+1)*64);
        ra1 = *(const float4*)(apl + (c+1)*64 + 4);
      }
      #pragma unroll
      for (int kcc = 0; kcc < 2; kcc++){
        short8 bfr[2];
        #pragma unroll
        for (int ct = 0; ct < 2; ct++)
          bfr[ct] = *(const short8*)(Bs1 + buf*8192 + (kcc*4 + q)*1024 + (wave*32 + ct*16 + m)*8);
        #pragma unroll
        for (int rt = 0; rt < 2; rt++){
          short8 a = *(const short8*)(As1 + (size_t)(buf*32 + rt*16 + m)*72 + kcc*32 + q*8);
          #pragma unroll
          for (int ct = 0; ct < 2; ct++)
            accP[rt][ct] = __builtin_amdgcn_mfma_f32_16x16x32_bf16(a, bfr[ct], accP[rt][ct], 0, 0, 0);
        }
      }
    }
    #pragma unroll
    for (int rt = 0; rt < 2; rt++)
      #pragma unroll
      for (int ct = 0; ct < 2; ct++){
        int col = wave*32 + ct*16 + m;
        #pragma unroll
        for (int r = 0; r < 4; r++)
          Pl[(size_t)(rt*16 + q*4 + r)*136 + col] = f2bf(accP[rt][ct][r]);
      }
    __syncthreads();

    // stage W0b [128 j][128 a] -> swizzled bf16 (overlay Bs1)
    int jB = t & 127, ah = t >> 7;
    const float* w0r = W0 + (size_t)jB*256 + 128 + ah*64;
    #pragma unroll
    for (int g2 = 0; g2 < 8; g2++){
      float4 u0 = *(const float4*)(w0r + g2*8);
      float4 u1 = *(const float4*)(w0r + g2*8 + 4);
      *(short8*)(Bs1 + (ah*8 + g2)*1024 + jB*8) = pack8(u0, u1);
    }
    __syncthreads();

    // stage-2: G[32][128] = P @ W0b^T, K=128 -> store Gt[j][l]
    f32x4 accG[2][2];
    #pragma unroll
    for (int rt = 0; rt < 2; rt++)
      #pragma unroll
      for (int ct = 0; ct < 2; ct++) accG[rt][ct] = (f32x4){0.f,0.f,0.f,0.f};
    #pragma unroll
    for (int kc = 0; kc < 4; kc++){
      short8 bfr[2];
      #pragma unroll
      for (int ct = 0; ct < 2; ct++)
        bfr[ct] = *(const short8*)(Bs1 + (kc*4 + q)*1024 + (wave*32 + ct*16 + m)*8);
      #pragma unroll
      for (int rt = 0; rt < 2; rt++){
        short8 a = *(const short8*)(Pl + (size_t)(rt*16 + m)*136 + kc*32 + q*8);
        #pragma unroll
        for (int ct = 0; ct < 2; ct++)
          accG[rt][ct] = __builtin_amdgcn_mfma_f32_16x16x32_bf16(a, bfr[ct], accG[rt][ct], 0, 0, 0);
      }
    }
    #pragma unroll
    for (int rt = 0; rt < 2; rt++)
      #pragma unroll
      for (int ct = 0; ct < 2; ct++){
        int j = wave*32 + ct*16 + m;
        #pragma unroll
        for (int r = 0; r < 4; r++)
          Gt[(size_t)j*LBL + l0 + rt*16 + q*4 + r] = f2bf(accG[rt][ct][r]);
      }
  }
}

// ============ k3: row-owner U-GEMM (A in registers, no A-LDS) + folded V + h0 + h1 + score ====
// 512 blocks x 512 thr (8 waves), 32 samples/block.
// U: wave w owns rows (w>>1)*16.. (+16) x cols (w&1)*64.. (+64); A frags global->reg->cvt_pk,
//    only B goes through LDS (double-buffered global_load_lds, 4 b128 frag reads/kcc... 8/iter).
// V: wave w owns V rows (w&1)*16.. x cols (w>>1)*32..; folded at c>=4 (2 chunks/iter), results
//    exchanged via LDS (sV) in the epilogue.
// Counted-vmcnt FIFO (traced): per iter pre-wait issue A(c+1)x4 [c<=10], G(c+1)x4 [3<=c<=10];
// wait vmcnt(4) c<3 / vmcnt(8) 3<=c<=10 / vmcnt(0) c==11; barrier; issue B(c+1)x2 [c<=10].
// Retires exactly {A(c),B(c),G(c)} each iter; A(c+1)/G(c+1) stay in flight across the barrier.
__global__ __launch_bounds__(512, 4) void k3(const float* __restrict__ T, const ushort_t* __restrict__ Msw,
                                          const float* __restrict__ KVg, const ushort_t* __restrict__ Gt,
                                          const int* __restrict__ tgt,
                                          const int* __restrict__ perm, const ushort_t* __restrict__ W1b,
                                          const float* __restrict__ b1, const float* __restrict__ W2,
                                          const float* __restrict__ b2, float* __restrict__ out){
  // main loop: Bs [2][8192]us @0 (32768)
  // epilogue:  sV [32][132]f @0 (16896) | h0s [64][136]us @16896 (17408) | sred [64][129]f @34304 (33024)
  __shared__ __align__(16) char uni[67328];
  __shared__ __align__(16) u64 bitsS[32*10];   // 80B pitch per row
  __shared__ float invs[32];

  int tid = threadIdx.x;
  int lane = tid & 63, w = tid >> 6;           // wave 0..7
  int m = lane & 15, q = lane >> 4;
  int rt4 = w >> 1, ch = w & 1;
  int r0 = blockIdx.x * 32;
  ushort_t* Bs_ = (ushort_t*)uni;              // [2][8192]

  // ---- issue B(0) ----
  {
    const char* gb = (const char*)Msw;
    char* lb = (char*)Bs_;
    gload_lds16(gb + tid*16,        lb + tid*16);
    gload_lds16(gb + 8192 + tid*16, lb + 8192 + tid*16);
  }
  // ---- issue tgt loads (wave w: rows w*4..w*4+3) ----
  int vv[4][8];
  #pragma unroll
  for (int rr = 0; rr < 4; rr++){
    const int* rp = tgt + (size_t)(r0 + w*4 + rr)*LBL;
    #pragma unroll
    for (int cc = 0; cc < 8; cc++) vv[rr][cc] = rp[cc*64 + lane];
  }
  // ---- A row for this lane: rt4 0,1 = pos rows, rt4 2,3 = perm-gathered neg rows ----
  int gr = (rt4 < 2) ? (r0 + rt4*16 + m) : perm[r0 + (rt4 - 2)*16 + m];
  const float* ap = T + (size_t)gr*HID + q*8;
  // A(0) into slot 0: fa[slot][kcc][half]
  float4 fa[2][2][2];
  #pragma unroll
  for (int kcc = 0; kcc < 2; kcc++){
    fa[0][kcc][0] = *(const float4*)(ap + kcc*32);
    fa[0][kcc][1] = *(const float4*)(ap + kcc*32 + 4);
  }

  // ---- consume tgt: ballot-pack (compiler wait retires tgt+B0, leaves A0 in flight) ----
  #pragma unroll
  for (int rr = 0; rr < 4; rr++){
    int row = w*4 + rr;
    int cnt = 0;
    #pragma unroll
    for (int cc = 0; cc < 8; cc++){
      u64 mm = __ballot(vv[rr][cc] != 0);
      if (lane == 0){ ((u64*)((char*)bitsS + row*80))[cc] = mm; cnt += __popcll(mm); }
    }
    if (lane == 0) invs[row] = 1.0f / (float)(cnt < 1 ? 1 : cnt);
  }

  // V operand pointers: wave w -> V col-quarter (w>>1), rows (w&1)*16..
  const ushort_t* gpt[2];
  #pragma unroll
  for (int ct = 0; ct < 2; ct++)
    gpt[ct] = Gt + (size_t)((w>>1)*32 + ct*16 + m)*LBL + q*8;
  int vrow = (w & 1)*16 + m;

  short8 gbuf[2][2][2];                        // [parity][sl][ct]
  f32x4 acc[4];                                // U: 4 col-tiles of wave's 16x64 tile
  f32x4 accV[2] = {{0,0,0,0},{0,0,0,0}};       // V: 2 col-tiles of wave's 16x32 tile
  #pragma unroll
  for (int ct = 0; ct < 4; ct++) acc[ct] = (f32x4){0.f,0.f,0.f,0.f};

  #pragma unroll
  for (int c = 0; c < 12; c++){
    int buf = c & 1;
    // pre-wait issue: A(c+1) into slot (c+1)&1
    if (c <= 10){
      #pragma unroll
      for (int kcc = 0; kcc < 2; kcc++){
        fa[(c+1)&1][kcc][0] = *(const float4*)(ap + (c+1)*64 + kcc*32);
        fa[(c+1)&1][kcc][1] = *(const float4*)(ap + (c+1)*64 + kcc*32 + 4);
      }
    }
    // pre-wait issue: G(c+1) (chunks 2(c-3), 2(c-3)+1 for iter c+1)
    if (c >= 3 && c <= 10){
      int sb = 2*(c-3);
      #pragma unroll
      for (int sl = 0; sl < 2; sl++)
        #pragma unroll
        for (int ct = 0; ct < 2; ct++)
          gbuf[(c+1)&1][sl][ct] = *(const short8*)(gpt[ct] + (size_t)(sb + sl)*32);
    }
    __builtin_amdgcn_sched_barrier(0);
    if (c == 11)    asm volatile("s_waitcnt vmcnt(0) lgkmcnt(0)" ::: "memory");
    else if (c < 3) asm volatile("s_waitcnt vmcnt(4) lgkmcnt(0)" ::: "memory");
    else            asm volatile("s_waitcnt vmcnt(8) lgkmcnt(0)" ::: "memory");
    __builtin_amdgcn_s_barrier();
    __builtin_amdgcn_sched_barrier(0);
    // post-barrier: issue B(c+1) into flipped buffer (readers of it drained by this barrier)
    if (c <= 10){
      const char* gb = (const char*)Msw + (size_t)(c+1)*16384;
      char* lb = (char*)(Bs_ + (buf^1)*8192);
      gload_lds16(gb + tid*16,        lb + tid*16);
      gload_lds16(gb + 8192 + tid*16, lb + 8192 + tid*16);
    }
    __builtin_amdgcn_sched_barrier(0);
    __builtin_amdgcn_s_setprio(1);
    // pack A(c) (HW cvt_pk, RNE == f2bf) and U-MFMA
    #pragma unroll
    for (int kcc = 0; kcc < 2; kcc++){
      short8 a = pack8_cvt(fa[c&1][kcc][0], fa[c&1][kcc][1]);
      #pragma unroll
      for (int ct = 0; ct < 4; ct++){
        short8 bfr = *(const short8*)(Bs_ + buf*8192 + (kcc*4 + q)*1024 + (ch*64 + ct*16 + m)*8);
        acc[ct] = __builtin_amdgcn_mfma_f32_16x16x32_bf16(a, bfr, acc[ct], 0, 0, 0);
      }
    }
    // folded V: chunks 2(c-4), 2(c-4)+1
    if (c >= 4){
      u64 w0 = *(const u64*)((const char*)bitsS + (size_t)vrow*80 + (size_t)(c-4)*8);
      u64 s0 = w0 >> (q*8);
      #pragma unroll
      for (int sl = 0; sl < 2; sl++){
        unsigned bb = (unsigned)(s0 >> (sl*32)) & 0xffu;
        short8 af;
        #pragma unroll
        for (int j = 0; j < 8; j++) af[j] = (short)(((bb >> j) & 1u) ? 0x3F80 : 0);
        #pragma unroll
        for (int ct = 0; ct < 2; ct++)
          accV[ct] = __builtin_amdgcn_mfma_f32_16x16x32_bf16(af, gbuf[c&1][sl][ct], accV[ct], 0, 0, 0);
      }
    }
    __builtin_amdgcn_s_setprio(0);
  }

  // ---- epilogue: exchange V through LDS, build h0, h1, reduce ----
  __syncthreads();                              // all Bs readers done; safe to overlay
  float* sV = (float*)uni;                      // [32][132]
  #pragma unroll
  for (int ct = 0; ct < 2; ct++){
    int vc = (w>>1)*32 + ct*16 + m;
    float kv = KVg[vc];
    #pragma unroll
    for (int r = 0; r < 4; r++){
      int vr = (w & 1)*16 + q*4 + r;
      sV[(size_t)vr*132 + vc] = accV[ct][r]*invs[vr] + kv;
    }
  }
  __syncthreads();

  ushort_t (*h0s)[136] = (ushort_t(*)[136])(uni + 16896);   // [64][136]: 0-31 pos, 32-63 neg
  #pragma unroll
  for (int ct = 0; ct < 4; ct++){
    int col = ch*64 + ct*16 + m;
    #pragma unroll
    for (int r = 0; r < 4; r++){
      int urow = rt4*16 + q*4 + r;              // 0..63
      float vw = sV[(size_t)(urow & 31)*132 + col];
      h0s[urow][col] = f2bf(fmaxf(acc[ct][r] + vw, 0.f));
    }
  }
  __syncthreads();

  float* sred = (float*)(uni + 34304);          // [64][129]
  int colh = w*16 + m;
  float w2c = W2[colh], b1c = b1[colh];
  float b2v = b2[0];
  #pragma unroll
  for (int rt2 = 0; rt2 < 4; rt2++){
    f32x4 accH = {0,0,0,0};
    #pragma unroll
    for (int kc = 0; kc < 4; kc++){
      short8 a = *(const short8*)&h0s[rt2*16 + m][kc*32 + q*8];
      short8 b = *(const short8*)(W1b + (size_t)colh*TR + kc*32 + q*8);
      accH = __builtin_amdgcn_mfma_f32_16x16x32_bf16(a, b, accH, 0, 0, 0);
    }
    #pragma unroll
    for (int r = 0; r < 4; r++){
      float sp = w2c * fmaxf(accH[r] + b1c, 0.f);
      sred[(size_t)(rt2*16 + q*4 + r)*129 + colh] = sp;
    }
  }
  __syncthreads();

  if (tid < 64){
    float s = b2v;
    #pragma unroll
    for (int n = 0; n < 128; n++) s += sred[(size_t)tid*129 + n];
    float val = (tid < 32) ? softplusf(-s) : softplusf(s);   // rows 0-31 = pos branch
    #pragma unroll
    for (int off = 32; off > 0; off >>= 1) val += __shfl_down(val, off);
    if (tid == 0) atomicAdd(out, val * (1.0f / (float)BATCH));
  }
}

extern "C" void kernel_launch(void* const* d_in, const int* in_sizes, int n_in,
                              void* d_out, int out_size, void* d_ws, size_t ws_size,
                              hipStream_t stream){
  const float* text = (const float*)d_in[0];
  const float* labe = (const float*)d_in[1];
  const int*   tgt  = (const int*)  d_in[2];
  const int*   perm = (const int*)  d_in[3];
  const float* Wt   = (const float*)d_in[4];
  const float* bt   = (const float*)d_in[5];
  const float* Wl   = (const float*)d_in[6];
  const float* bl   = (const float*)d_in[7];
  const float* W0   = (const float*)d_in[8];
  const float* b0   = (const float*)d_in[9];
  const float* W1   = (const float*)d_in[10];
  const float* b1   = (const float*)d_in[11];
  const float* W2   = (const float*)d_in[12];
  const float* b2   = (const float*)d_in[13];

  char* wsb = (char*)d_ws;
  size_t off = 0;
  auto alloc = [&](size_t bytes){
    size_t r = off;
    off += (bytes + 255) & ~(size_t)255;
    return r;
  };
  ushort_t* MSW = (ushort_t*)(wsb + alloc((size_t)TR*HID*2));
  ushort_t* GT  = (ushort_t*)(wsb + alloc((size_t)TR*LBL*2));
  ushort_t* W1B = (ushort_t*)(wsb + alloc((size_t)TR*TR*2));
  float*    KV  = (float*)   (wsb + alloc((size_t)TR*4));
  float*    out = (float*)d_out;
  (void)ws_size; (void)in_sizes; (void)n_in; (void)out_size;

  k1<<<145, 256, 0, stream>>>(W0, Wt, Wl, bt, bl, b0, W1, labe, MSW, W1B, GT, KV, out);
  k3<<<512, 512, 0, stream>>>(text, MSW, KV, GT, tgt, perm, W1B, b1, W2, b2, out);
}

// Round 7
// 164.783 us; speedup vs baseline: 1.1472x; 1.1472x over previous
//
#include <hip/hip_runtime.h>
#include <math.h>

#define BATCH 16384
#define LBL   512
#define HID   768
#define TR    128

typedef unsigned long long u64;
typedef unsigned short ushort_t;
typedef __attribute__((ext_vector_type(8))) short short8;
typedef __attribute__((ext_vector_type(4))) float f32x4;

__device__ __forceinline__ ushort_t f2bf(float f){
  unsigned u = __builtin_bit_cast(unsigned, f);
  u += 0x7FFFu + ((u >> 16) & 1u);
  return (ushort_t)(u >> 16);
}
// HW packed f32->bf16 (RNE, verified bit-identical to f2bf in R5): 4 inst instead of ~56.
__device__ __forceinline__ short8 pack8_cvt(float4 x, float4 y){
  union { short8 s; unsigned u[4]; } r;
  asm("v_cvt_pk_bf16_f32 %0, %1, %2" : "=v"(r.u[0]) : "v"(x.x), "v"(x.y));
  asm("v_cvt_pk_bf16_f32 %0, %1, %2" : "=v"(r.u[1]) : "v"(x.z), "v"(x.w));
  asm("v_cvt_pk_bf16_f32 %0, %1, %2" : "=v"(r.u[2]) : "v"(y.x), "v"(y.y));
  asm("v_cvt_pk_bf16_f32 %0, %1, %2" : "=v"(r.u[3]) : "v"(y.z), "v"(y.w));
  return r.s;
}
__device__ __forceinline__ float softplusf(float x){
  return fmaxf(x, 0.0f) + log1pf(expf(-fabsf(x)));
}
__device__ __forceinline__ void gload_lds16(const void* g, void* l){
  __builtin_amdgcn_global_load_lds((const __attribute__((address_space(1))) void*)g,
                                   (__attribute__((address_space(3))) void*)l, 16, 0, 0);
}

// ============ k1: M = W0a@Wt, Q = W0b@Wl (swizzled bf16), W1->bf16, KV, zero out ============
// (R1's proven k1 — 257 blocks.)
// Swizzle: element (n, k) of a [128 n][768 k] B-matrix at ((k>>3)<<10) + (n<<3) + (k&7);
// chunk kc (64 k) = contiguous 16 KB at elem offset kc*8192 -> global_load_lds ready.
__global__ __launch_bounds__(256) void k1(
    const float* __restrict__ W0, const float* __restrict__ Wt, const float* __restrict__ Wl,
    const float* __restrict__ bt, const float* __restrict__ bl, const float* __restrict__ b0,
    const float* __restrict__ W1,
    ushort_t* __restrict__ Msw, ushort_t* __restrict__ Qsw, ushort_t* __restrict__ W1B,
    float* __restrict__ KV, float* __restrict__ out){
  __shared__ float sw[TR];
  int bi = blockIdx.x, t = threadIdx.x;
  if (bi < 256){
    int i = bi & 127;
    int isQ = bi >> 7;
    const float* src = isQ ? Wl : Wt;
    ushort_t* dst = isQ ? Qsw : Msw;
    if (t < TR) sw[t] = W0[(size_t)i*256 + isQ*128 + t];
    if (!isQ && t < 128) W1B[i*128 + t] = f2bf(W1[i*128 + t]);
    __syncthreads();
    int c = t;
    float a0 = 0.f, a1 = 0.f, a2 = 0.f;
    #pragma unroll 8
    for (int a = 0; a < 128; a++){
      float w = sw[a];
      const float* r = src + (size_t)a*HID;
      a0 = fmaf(w, r[c], a0);
      a1 = fmaf(w, r[c+256], a1);
      a2 = fmaf(w, r[c+512], a2);
    }
    int c7 = c & 7;
    dst[(((c      )>>3)<<10) + (i<<3) + c7] = f2bf(a0);
    dst[(((c + 256)>>3)<<10) + (i<<3) + c7] = f2bf(a1);
    dst[(((c + 512)>>3)<<10) + (i<<3) + c7] = f2bf(a2);
  } else {
    if (t < TR){
      float s = b0[t];
      const float* r = W0 + (size_t)t*256;
      for (int a = 0; a < 128; a++) s = fmaf(r[a], bt[a], s);
      for (int a = 0; a < 128; a++) s = fmaf(r[128+a], bl[a], s);
      KV[t] = s;
    }
    if (t == 0) out[0] = 0.f;
  }
}

// 32-row x 128-col tile GEMM, K=768. B pre-swizzled. A fp32 rows -> bf16 LDS.
// As_: [2][32][80] ushort; Bs_: [2][8192] ushort.
__device__ __forceinline__ void gemm768_32(const float* ap, const ushort_t* Bsw,
                                           ushort_t* As_, ushort_t* Bs_,
                                           int tid, int wave, int m, int q,
                                           f32x4 acc[2][2]){
  float4 ra0 = *(const float4*)ap;
  float4 ra1 = *(const float4*)(ap + 4);
  {
    const char* gb = (const char*)Bsw;
    char* lb = (char*)Bs_;
    #pragma unroll
    for (int p = 0; p < 4; p++)
      gload_lds16(gb + p*4096 + tid*16, lb + p*4096 + tid*16);
  }
  #pragma unroll
  for (int rt = 0; rt < 2; rt++)
    #pragma unroll
    for (int ct = 0; ct < 2; ct++)
      acc[rt][ct] = (f32x4){0.f,0.f,0.f,0.f};

  for (int c = 0; c < 12; c++){
    int buf = c & 1;
    *(short8*)(As_ + (size_t)(buf*32 + (tid >> 3))*80 + (tid & 7)*8) = pack8_cvt(ra0, ra1);
    __syncthreads();
    if (c < 11){
      ra0 = *(const float4*)(ap + (c+1)*64);
      ra1 = *(const float4*)(ap + (c+1)*64 + 4);
      const char* gb = (const char*)Bsw + (size_t)(c+1)*16384;
      char* lb = (char*)(Bs_ + (buf^1)*8192);
      #pragma unroll
      for (int p = 0; p < 4; p++)
        gload_lds16(gb + p*4096 + tid*16, lb + p*4096 + tid*16);
    }
    #pragma unroll
    for (int kcc = 0; kcc < 2; kcc++){
      short8 bfr[2];
      #pragma unroll
      for (int ct = 0; ct < 2; ct++)
        bfr[ct] = *(const short8*)(Bs_ + buf*8192 + (kcc*4 + q)*1024 + (wave*32 + ct*16 + m)*8);
      #pragma unroll
      for (int rt = 0; rt < 2; rt++){
        short8 a = *(const short8*)(As_ + (size_t)(buf*32 + rt*16 + m)*80 + kcc*32 + q*8);
        #pragma unroll
        for (int ct = 0; ct < 2; ct++)
          acc[rt][ct] = __builtin_amdgcn_mfma_f32_16x16x32_bf16(a, bfr[ct], acc[rt][ct], 0, 0, 0);
      }
    }
  }
}

// ============ k2: G = labe @ Q^T (16 blocks) ============
__global__ __launch_bounds__(256) void k2(
    const float* __restrict__ labe, const ushort_t* __restrict__ Qsw,
    ushort_t* __restrict__ Gt){
  __shared__ __align__(16) char uni[43008];
  int bi = blockIdx.x, tid = threadIdx.x;
  int lane = tid & 63, wave = tid >> 6;
  int m = lane & 15, q = lane >> 4;
  ushort_t* Bs_ = (ushort_t*)uni;
  ushort_t* As_ = (ushort_t*)(uni + 32768);

  int l0 = bi * 32;
  int arow = tid >> 3, ak = (tid & 7) * 8;
  f32x4 accG[2][2];
  gemm768_32(labe + (size_t)(l0 + arow)*HID + ak, Qsw, As_, Bs_, tid, wave, m, q, accG);
  __syncthreads();
  ushort_t (*GTs)[40] = (ushort_t(*)[40])uni;   // [128][40]
  #pragma unroll
  for (int rt = 0; rt < 2; rt++)
    #pragma unroll
    for (int ct = 0; ct < 2; ct++){
      int col = wave*32 + ct*16 + m;
      #pragma unroll
      for (int r = 0; r < 4; r++)
        GTs[col][rt*16 + q*4 + r] = f2bf(accG[rt][ct][r]);
    }
  __syncthreads();
  int gi = tid >> 1, half = tid & 1;
  ushort_t* dstp = Gt + (size_t)gi*LBL + l0 + half*16;
  *(short8*)(dstp)     = *(const short8*)&GTs[gi][half*16];
  *(short8*)(dstp + 8) = *(const short8*)&GTs[gi][half*16 + 8];
}

// ============ k3: R2's proven 64-row U-GEMM + bitpack + V + h0 + h1 + score ============
// 512 blocks x 512 thr (8 waves), 32 samples/block; wave w owns output cols w*16..w*16+15.
// T4 counted-vmcnt main loop (R2 ladder, best measured 42.1us). Only change vs R2: pv/nv
// packs use pack8_cvt (bit-identical, ~112 VALU ops -> 8 per thread per iter).
__global__ __launch_bounds__(512, 4) void k3(const float* __restrict__ T, const ushort_t* __restrict__ Msw,
                                          const float* __restrict__ KV, const ushort_t* __restrict__ Gt,
                                          const int* __restrict__ tgt,
                                          const int* __restrict__ perm, const ushort_t* __restrict__ W1b,
                                          const float* __restrict__ b1, const float* __restrict__ W2,
                                          const float* __restrict__ b2, float* __restrict__ out){
  __shared__ __align__(16) char uni[51200];
  __shared__ __align__(16) u64 bitsS[32*10];   // 80B pitch per row
  __shared__ float invs[32];

  int tid = threadIdx.x;
  int lane = tid & 63, wave = tid >> 6;        // wave 0..7
  int m = lane & 15, q = lane >> 4;
  int r0 = blockIdx.x * 32;
  ushort_t* Bs_ = (ushort_t*)uni;              // [2][8192]
  ushort_t* As_ = (ushort_t*)(uni + 32768);    // [2][64][72]

  // ---- issue B(0) ----
  {
    const char* gb = (const char*)Msw;
    char* lb = (char*)Bs_;
    gload_lds16(gb + tid*16,        lb + tid*16);
    gload_lds16(gb + 8192 + tid*16, lb + 8192 + tid*16);
  }
  // ---- issue tgt loads (wave w: rows w*4..w*4+3) ----
  int vv[4][8];
  #pragma unroll
  for (int rr = 0; rr < 4; rr++){
    const int* rp = tgt + (size_t)(r0 + wave*4 + rr)*LBL;
    #pragma unroll
    for (int cc = 0; cc < 8; cc++) vv[rr][cc] = rp[cc*64 + lane];
  }
  // ---- A rows: 0..31 = text[r0+i], 32..63 = text[perm[r0+i]]; prefetch depth 2 ----
  int ar = tid >> 3, ak = (tid & 7) * 8;       // ar 0..63
  int arow = (ar < 32) ? (r0 + ar) : perm[r0 + ar - 32];
  const float* app = T + (size_t)arow*HID + ak;
  float4 aa0[2], aa1[2];
  aa0[0] = *(const float4*)(app);      aa1[0] = *(const float4*)(app + 4);
  aa0[1] = *(const float4*)(app + 64); aa1[1] = *(const float4*)(app + 68);

  // ---- consume tgt: ballot-pack (drains VMEM queue once, pre-loop) ----
  #pragma unroll
  for (int rr = 0; rr < 4; rr++){
    int row = wave*4 + rr;
    int cnt = 0;
    #pragma unroll
    for (int cc = 0; cc < 8; cc++){
      u64 mm = __ballot(vv[rr][cc] != 0);
      if (lane == 0){ ((u64*)((char*)bitsS + row*80))[cc] = mm; cnt += __popcll(mm); }
    }
    if (lane == 0) invs[row] = 1.0f / (float)(cnt < 1 ? 1 : cnt);
  }

  f32x4 acc[4];
  #pragma unroll
  for (int rt = 0; rt < 4; rt++) acc[rt] = (f32x4){0.f,0.f,0.f,0.f};

  #pragma unroll
  for (int c = 0; c < 12; c++){
    int buf = c & 1;
    // step1: pack A(c) -> As_ (HW cvt_pk, bit-identical to f2bf)
    *(short8*)(As_ + (size_t)(buf*64 + ar)*72 + ak)      = pack8_cvt(aa0[buf], aa1[buf]);
    // step2: issue A(c+2) into freed slot
    if (c < 10){
      aa0[buf] = *(const float4*)(app + (c+2)*64);
      aa1[buf] = *(const float4*)(app + (c+2)*64 + 4);
    }
    // step3/4: counted wait + raw barrier (B(c) done; A(c+2) may stay in flight)
    __builtin_amdgcn_sched_barrier(0);
    if (c < 10) asm volatile("s_waitcnt vmcnt(2) lgkmcnt(0)" ::: "memory");
    else        asm volatile("s_waitcnt vmcnt(0) lgkmcnt(0)" ::: "memory");
    __builtin_amdgcn_s_barrier();
    __builtin_amdgcn_sched_barrier(0);
    // step5: issue B(c+1) (safe: buf^1 readers drained by barrier(c))
    if (c < 11){
      const char* gb = (const char*)Msw + (size_t)(c+1)*16384;
      char* lb = (char*)(Bs_ + (buf^1)*8192);
      gload_lds16(gb + tid*16,        lb + tid*16);
      gload_lds16(gb + 8192 + tid*16, lb + 8192 + tid*16);
    }
    __builtin_amdgcn_sched_barrier(0);
    // step6: MFMA(c)
    __builtin_amdgcn_s_setprio(1);
    #pragma unroll
    for (int kcc = 0; kcc < 2; kcc++){
      short8 bfr = *(const short8*)(Bs_ + buf*8192 + (kcc*4 + q)*1024 + (wave*16 + m)*8);
      #pragma unroll
      for (int rt = 0; rt < 4; rt++){
        short8 a = *(const short8*)(As_ + (size_t)(buf*64 + rt*16 + m)*72 + kcc*32 + q*8);
        acc[rt] = __builtin_amdgcn_mfma_f32_16x16x32_bf16(a, bfr, acc[rt], 0, 0, 0);
      }
    }
    __builtin_amdgcn_s_setprio(0);
  }

  // ---- V = mask @ G (K=512), Gt prefetch 2-deep ----
  const unsigned char* bits_b = (const unsigned char*)bitsS;
  f32x4 accV[2] = {{0,0,0,0},{0,0,0,0}};
  const ushort_t* gp = Gt + (size_t)(wave*16 + m)*LBL + q*8;
  short8 bv0 = *(const short8*)(gp);
  short8 bv1 = *(const short8*)(gp + 32);
  for (int c = 0; c < 16; c++){
    short8 bn = bv1;
    if (c < 14) bn = *(const short8*)(gp + (size_t)(c+2)*32);
    #pragma unroll
    for (int rt = 0; rt < 2; rt++){
      unsigned bb = bits_b[(rt*16 + m)*80 + c*4 + q];
      short8 a;
      #pragma unroll
      for (int j = 0; j < 8; j++) a[j] = (short)(((bb >> j) & 1u) ? 0x3F80 : 0);
      accV[rt] = __builtin_amdgcn_mfma_f32_16x16x32_bf16(a, bv0, accV[rt], 0, 0, 0);
    }
    bv0 = bv1; bv1 = bn;
  }

  // ---- h0 both branches -> LDS (overlay on uni; GEMM LDS dead now) ----
  __syncthreads();
  ushort_t (*h0s)[136] = (ushort_t(*)[136])uni;   // [64][136]: rows 0-31 pos, 32-63 neg
  float* sred = (float*)(uni + 17408);            // [64][129] floats
  int col = wave*16 + m;
  float kv = KV[col];
  #pragma unroll
  for (int rt = 0; rt < 2; rt++){
    #pragma unroll
    for (int r = 0; r < 4; r++){
      int rowl = rt*16 + q*4 + r;
      float vvv = accV[rt][r] * invs[rowl] + kv;
      h0s[rowl][col]      = f2bf(fmaxf(acc[rt][r]   + vvv, 0.f));
      h0s[32 + rowl][col] = f2bf(fmaxf(acc[rt+2][r] + vvv, 0.f));
    }
  }
  __syncthreads();

  float w2c = W2[col], b1c = b1[col];
  float b2v = b2[0];
  #pragma unroll
  for (int rt2 = 0; rt2 < 4; rt2++){
    f32x4 accH = {0,0,0,0};
    #pragma unroll
    for (int kc = 0; kc < 4; kc++){
      short8 a = *(const short8*)&h0s[rt2*16 + m][kc*32 + q*8];
      short8 b = *(const short8*)(W1b + (size_t)col*TR + kc*32 + q*8);
      accH = __builtin_amdgcn_mfma_f32_16x16x32_bf16(a, b, accH, 0, 0, 0);
    }
    #pragma unroll
    for (int r = 0; r < 4; r++){
      float sp = w2c * fmaxf(accH[r] + b1c, 0.f);
      sred[(size_t)(rt2*16 + q*4 + r)*129 + col] = sp;
    }
  }
  __syncthreads();

  if (tid < 64){
    float s = b2v;
    #pragma unroll
    for (int n = 0; n < 128; n++) s += sred[(size_t)tid*129 + n];
    float val = (tid < 32) ? softplusf(-s) : softplusf(s);   // rows 0-31 = pos branch
    #pragma unroll
    for (int off = 32; off > 0; off >>= 1) val += __shfl_down(val, off);
    if (tid == 0) atomicAdd(out, val * (1.0f / (float)BATCH));
  }
}

extern "C" void kernel_launch(void* const* d_in, const int* in_sizes, int n_in,
                              void* d_out, int out_size, void* d_ws, size_t ws_size,
                              hipStream_t stream){
  const float* text = (const float*)d_in[0];
  const float* labe = (const float*)d_in[1];
  const int*   tgt  = (const int*)  d_in[2];
  const int*   perm = (const int*)  d_in[3];
  const float* Wt   = (const float*)d_in[4];
  const float* bt   = (const float*)d_in[5];
  const float* Wl   = (const float*)d_in[6];
  const float* bl   = (const float*)d_in[7];
  const float* W0   = (const float*)d_in[8];
  const float* b0   = (const float*)d_in[9];
  const float* W1   = (const float*)d_in[10];
  const float* b1   = (const float*)d_in[11];
  const float* W2   = (const float*)d_in[12];
  const float* b2   = (const float*)d_in[13];

  char* wsb = (char*)d_ws;
  size_t off = 0;
  auto alloc = [&](size_t bytes){
    size_t r = off;
    off += (bytes + 255) & ~(size_t)255;
    return r;
  };
  ushort_t* MSW = (ushort_t*)(wsb + alloc((size_t)TR*HID*2));
  ushort_t* QSW = (ushort_t*)(wsb + alloc((size_t)TR*HID*2));
  ushort_t* GT  = (ushort_t*)(wsb + alloc((size_t)TR*LBL*2));
  ushort_t* W1B = (ushort_t*)(wsb + alloc((size_t)TR*TR*2));
  float*    KV  = (float*)   (wsb + alloc((size_t)TR*4));
  float*    out = (float*)d_out;
  (void)ws_size; (void)in_sizes; (void)n_in; (void)out_size;

  k1<<<257, 256, 0, stream>>>(W0, Wt, Wl, bt, bl, b0, W1, MSW, QSW, W1B, KV, out);
  k2<<<16, 256, 0, stream>>>(labe, QSW, GT);
  k3<<<512, 512, 0, stream>>>(text, MSW, KV, GT, tgt, perm, W1B, b1, W2, b2, out);
}